// Round 17
// baseline (454.449 us; speedup 1.0000x reference)
//
#include <hip/hip_runtime.h>
#include <math.h>

#define DMODEL 1024
#define SIXD   6144
#define NHEAD  16
#define HEADD  64
#define LSEQ   1024
#define NBATCH 8
#define MROWS  8192   // NBATCH*LSEQ

typedef unsigned short ushort_t;
typedef __attribute__((ext_vector_type(8))) short bf16x8;
typedef __attribute__((ext_vector_type(4))) float f32x4;

__device__ __forceinline__ unsigned short f2bf(float f) {
  unsigned int u = __float_as_uint(f);
  u += 0x7fff + ((u >> 16) & 1);          // round-to-nearest-even
  return (unsigned short)(u >> 16);
}

__device__ __forceinline__ void gload_lds16(const void* g, void* l) {
  __builtin_amdgcn_global_load_lds(
      (const __attribute__((address_space(1))) unsigned int*)g,
      (__attribute__((address_space(3))) unsigned int*)l, 16, 0, 0);
}

// ---------------- weight transpose + cast: W[K][N] f32 -> WT[N][K] bf16 ----
__global__ void tcast_kernel(const float* __restrict__ W, ushort_t* __restrict__ WT,
                             int K, int N) {
  __shared__ float tile[32][33];
  int tx = threadIdx.x & 31, ty = threadIdx.x >> 5;
  int n0 = blockIdx.x * 32, k0 = blockIdx.y * 32;
#pragma unroll
  for (int r = 0; r < 4; ++r)
    tile[ty + 8*r][tx] = W[(size_t)(k0 + ty + 8*r) * N + n0 + tx];
  __syncthreads();
#pragma unroll
  for (int r = 0; r < 4; ++r)
    WT[(size_t)(n0 + ty + 8*r) * K + k0 + tx] = f2bf(tile[tx][ty + 8*r]);
}

// ---------------- V transpose: qkv[row][2048+h*64+d] -> vT[bh][d][kv] ------
__global__ __launch_bounds__(256) void vtrans_kernel(
    const ushort_t* __restrict__ qkvb, ushort_t* __restrict__ vT) {
  __shared__ ushort_t tile[128][66];   // pad 66: conflict-light transpose
  int bh = blockIdx.x;                 // 0..127
  int kt = blockIdx.y;                 // 0..7 (128 kv rows each)
  int b = bh >> 4, h = bh & 15;
  int tid = threadIdx.x;
#pragma unroll
  for (int i = 0; i < 4; ++i) {
    int flat = tid + 256 * i;          // 1024 chunks of 8 elems
    int r = flat >> 3, c8 = flat & 7;
    bf16x8 v = *(const bf16x8*)((const short*)qkvb +
        (size_t)(b * LSEQ + kt * 128 + r) * 3072 + 2048 + h * 64 + c8 * 8);
#pragma unroll
    for (int j = 0; j < 8; ++j) tile[r][c8 * 8 + j] = (ushort_t)v[j];
  }
  __syncthreads();
#pragma unroll
  for (int i = 0; i < 4; ++i) {
    int d = i * 16 + (tid >> 4);
    int kc = tid & 15;
    bf16x8 ov;
#pragma unroll
    for (int j = 0; j < 8; ++j) ov[j] = (short)tile[kc * 8 + j][d];
    *(bf16x8*)((short*)vT + (size_t)(bh * 64 + d) * 1024 + kt * 128 + kc * 8) = ov;
  }
}

// ---------------- adaLN: ssg[b][j] = silu(c[b]) @ ada_w[:,j] + ada_b[j] ----
__global__ void ada_kernel(const float* __restrict__ c, const float* __restrict__ ada_w,
                           const float* __restrict__ ada_b, float* __restrict__ ssg) {
  __shared__ float s[DMODEL];
  int b = blockIdx.y;
  int j = blockIdx.x * 256 + threadIdx.x;
  for (int i = threadIdx.x; i < DMODEL; i += 256) {
    float v = c[b * DMODEL + i];
    s[i] = v / (1.0f + __expf(-v));
  }
  __syncthreads();
  float acc = ada_b[j];
#pragma unroll 8
  for (int k = 0; k < DMODEL; ++k)
    acc = fmaf(s[k], ada_w[(size_t)k * SIXD + j], acc);
  ssg[b * SIXD + j] = acc;
}

// ---------------- LayerNorm + modulate + cast to bf16 ---------------------
__global__ __launch_bounds__(256) void ln_mod_kernel(
    const float* __restrict__ xin, const float* __restrict__ lw,
    const float* __restrict__ lb, const float* __restrict__ ssg,
    int shift_off, int scale_off, ushort_t* __restrict__ outB) {
  int row = blockIdx.x;
  int b = row >> 10;
  int tid = threadIdx.x;
  float4 v = ((const float4*)xin)[(size_t)row * 256 + tid];
  float sum = v.x + v.y + v.z + v.w;
  float sq  = v.x*v.x + v.y*v.y + v.z*v.z + v.w*v.w;
#pragma unroll
  for (int m = 32; m; m >>= 1) { sum += __shfl_xor(sum, m); sq += __shfl_xor(sq, m); }
  __shared__ float rbuf[8];
  int w = tid >> 6, lane = tid & 63;
  if (lane == 0) { rbuf[w] = sum; rbuf[4 + w] = sq; }
  __syncthreads();
  sum = rbuf[0] + rbuf[1] + rbuf[2] + rbuf[3];
  sq  = rbuf[4] + rbuf[5] + rbuf[6] + rbuf[7];
  float mu  = sum * (1.0f / 1024.0f);
  float var = sq * (1.0f / 1024.0f) - mu * mu;
  float rs  = rsqrtf(var + 1e-5f);
  const float* sg = ssg + b * SIXD;
  float vv[4] = {v.x, v.y, v.z, v.w};
  ushort4 pk;
  unsigned short* pks = (unsigned short*)&pk;
#pragma unroll
  for (int j = 0; j < 4; ++j) {
    int d = tid * 4 + j;
    float h = (vv[j] - mu) * rs * lw[d] + lb[d];
    h = h * (1.0f + sg[scale_off + d]) + sg[shift_off + d];
    pks[j] = f2bf(h);
  }
  ((ushort4*)outB)[(size_t)row * 256 + tid] = pk;
}

// ---------------- GEMM: C[M][N] = A[M][K]bf16 @ BT[N][K]bf16^T + epilogue --
// 128x128 tile, BK=32, 256 thr; ring-3 LDS slots (16 KB each = 48 KB -> 3
// blocks/CU) with counted vmcnt — the hazard ledger HW-verified by the r16
// attention kernel: STAGE(t+2) targets the slot dead since step t-1's
// closing barrier; end-of-step waits vmcnt(4) (t+1's loads land, t+2's stay
// in flight across the raw s_barrier). Accumulation order identical to the
// BK=64 version (same K sequence) -> bit-identical results.
// 64B-row swizzle: byte ^= (row&3)<<4 on both staging source and ds_read.
template <int EPI>
__global__ __launch_bounds__(256, 3) void gemm_kernel(
    const ushort_t* __restrict__ A, const ushort_t* __restrict__ BT,
    const float* __restrict__ bias, const float* __restrict__ ssg,
    const float* resid, float* outF, ushort_t* __restrict__ outB,
    int N, int K, int gate_off, int gxs) {
  __shared__ __align__(16) char SM[49152];   // 3 slots x (A 8K | B 8K)
  int tid = threadIdx.x, lane = tid & 63, w = tid >> 6;
  int l15 = lane & 15, g = lane >> 4;
  // 3-level remap (XCD chunk -> GX-column groups over 8 by-rows)
  int orig = blockIdx.x;
  int xcd = orig & 7;
  int idx = orig >> 3;
  int bxi = idx & ((1 << gxs) - 1);
  int byl = (idx >> gxs) & 7;
  int bxg = idx >> (gxs + 3);
  int bx = (bxg << gxs) + bxi;
  int by = (xcd << 3) + byl;
  int m0 = by * 128, n0 = bx * 128;
  int wrow = (w >> 1) * 64, wcol = (w & 1) * 64;
  f32x4 zero = {0.f, 0.f, 0.f, 0.f};
  f32x4 acc[4][4];
#pragma unroll
  for (int i = 0; i < 4; ++i)
#pragma unroll
    for (int j = 0; j < 4; ++j) acc[i][j] = zero;

  // staging sources (pre-swizzled for 64B rows, tile-invariant)
  const char* asrc[2];
  const char* bsrc[2];
#pragma unroll
  for (int ch = 0; ch < 2; ++ch) {
    int flat = ch * 4096 + tid * 16;
    int row = flat >> 6;                       // 64 B per row (32 bf16)
    int colb = (flat & 63) ^ ((row & 3) << 4); // inverse-swizzled source
    asrc[ch] = (const char*)A  + ((size_t)(m0 + row) * K) * 2 + colb;
    bsrc[ch] = (const char*)BT + ((size_t)(n0 + row) * K) * 2 + colb;
  }

  // STAGE(tile, slot): 4 loads/thread (2 A + 2 B)
  auto STAGE = [&](int tt, int s) {
    size_t ko = (size_t)tt * 64;               // 32 bf16 = 64 B per K-step
    char* base = SM + s * 16384;
#pragma unroll
    for (int ch = 0; ch < 2; ++ch) {
      gload_lds16(asrc[ch] + ko, base + ch * 4096 + tid * 16);
      gload_lds16(bsrc[ch] + ko, base + 8192 + ch * 4096 + tid * 16);
    }
  };

  int T = K >> 5;
  // prologue: stage tiles 0,1 into slots 0,1; wait tile 0 only
  STAGE(0, 0);
  STAGE(1, 1);
  asm volatile("s_waitcnt vmcnt(4)" ::: "memory");
  asm volatile("s_barrier" ::: "memory");

  int s0 = 0;
  for (int t = 0; t < T; ++t) {
    int s2 = s0 + 2; if (s2 >= 3) s2 -= 3;
    if (t + 2 < T) STAGE(t + 2, s2);
    const char* ab = SM + s0 * 16384;
    const char* bb = ab + 8192;
    bf16x8 af[4], bfr[4];
#pragma unroll
    for (int i = 0; i < 4; ++i) {
      int ar = wrow + i * 16 + l15;
      af[i]  = *(const bf16x8*)(ab + ar * 64 + ((g * 16) ^ ((ar & 3) << 4)));
      int br = wcol + i * 16 + l15;
      bfr[i] = *(const bf16x8*)(bb + br * 64 + ((g * 16) ^ ((br & 3) << 4)));
    }
    __builtin_amdgcn_s_setprio(1);
#pragma unroll
    for (int i = 0; i < 4; ++i)
#pragma unroll
      for (int j = 0; j < 4; ++j)
        acc[i][j] = __builtin_amdgcn_mfma_f32_16x16x32_bf16(af[i], bfr[j], acc[i][j], 0, 0, 0);
    __builtin_amdgcn_s_setprio(0);
    // end of step: t+1's loads must land; t+2's stay in flight
    if (t + 2 < T)      asm volatile("s_waitcnt vmcnt(4)" ::: "memory");
    else if (t + 1 < T) asm volatile("s_waitcnt vmcnt(0)" ::: "memory");
    if (t + 1 < T)      asm volatile("s_barrier" ::: "memory");
    s0 = s0 + 1; if (s0 >= 3) s0 -= 3;
  }
  // epilogue
#pragma unroll
  for (int i = 0; i < 4; ++i)
#pragma unroll
    for (int j = 0; j < 4; ++j)
#pragma unroll
      for (int r = 0; r < 4; ++r) {
        int grow = m0 + wrow + i * 16 + g * 4 + r;
        int gcol = n0 + wcol + j * 16 + l15;
        float v = acc[i][j][r] + bias[gcol];
        if (EPI == 0) {
          outB[(size_t)grow * N + gcol] = f2bf(v);
        } else if (EPI == 1 || EPI == 3) {
          int bb2 = grow >> 10;
          float gate = ssg[bb2 * SIXD + gate_off + gcol];
          size_t idx2 = (size_t)grow * N + gcol;   // N==1024 here
          outF[idx2] = resid[idx2] + gate * v;
        } else {  // gelu tanh-approx
          float u = v;
          float t2 = 0.7978845608028654f * (u + 0.044715f * u * u * u);
          float e = __expf(2.0f * t2);
          float th = 1.0f - 2.0f / (e + 1.0f);
          outB[(size_t)grow * N + gcol] = f2bf(0.5f * u * (1.0f + th));
        }
      }
}

// ---------------- flash attention (ring-3 K/V, counted vmcnt, 2 q-tiles) ---
// grid (8 q-tiles of 128 rows, 128 b*h), 256 threads (4 waves).
__global__ __launch_bounds__(256, 2) void attn_kernel(
    const ushort_t* __restrict__ qkv,   // [8192][3072] bf16 (q|k|v)
    const ushort_t* __restrict__ vT,    // [128 bh][64 d][1024 kv] bf16
    ushort_t* __restrict__ aout) {      // [8192][1024] bf16
  // K slots [0,24576) ; V^T slots [24576,49152) ; lbuf [49152,+256)
  __shared__ __align__(16) char SM[49408];
  float* lbuf = (float*)(SM + 49152);
  int tid = threadIdx.x, lane = tid & 63, w = tid >> 6;
  int l15 = lane & 15, g = lane >> 4;
  int qt = blockIdx.x, bh = blockIdx.y;
  int b = bh >> 4, h = bh & 15;
  const float sc = 0.18033688f;  // (1/sqrt(64)) * log2(e)

  // Q fragments for both q-sets (B operand), scaled by sc (bf16 repack)
  bf16x8 aq[2], aq2[2];
  {
    int qrow = qt * 128 + w * 16 + l15;
    const short* qp = (const short*)qkv + (size_t)(b * LSEQ + qrow) * 3072 + h * 64 + g * 8;
    aq[0] = *(const bf16x8*)qp;
    aq[1] = *(const bf16x8*)(qp + 32);
    const short* qp2 = qp + (size_t)64 * 3072;
    aq2[0] = *(const bf16x8*)qp2;
    aq2[1] = *(const bf16x8*)(qp2 + 32);
#pragma unroll
    for (int ks = 0; ks < 2; ++ks) {
#pragma unroll
      for (int s = 0; s < 2; ++s) {
        union { bf16x8 v; unsigned short u[8]; } qi, qo;
        qi.v = s ? aq2[ks] : aq[ks];
#pragma unroll
        for (int j = 0; j < 8; j += 2) {
          float lo = __uint_as_float((unsigned)qi.u[j] << 16) * sc;
          float hi = __uint_as_float((unsigned)qi.u[j + 1] << 16) * sc;
          unsigned pkd;
          asm("v_cvt_pk_bf16_f32 %0, %1, %2" : "=v"(pkd) : "v"(lo), "v"(hi));
          qo.u[j] = (unsigned short)(pkd & 0xffff);
          qo.u[j + 1] = (unsigned short)(pkd >> 16);
        }
        if (s) aq2[ks] = qo.v; else aq[ks] = qo.v;
      }
    }
  }

  // staging sources (pre-swizzled; tile-invariant part)
  const char* ksrc[2];   // K rows = kv (stride 3072*2 B)
  const char* vsrc[2];   // V^T rows = d (stride 1024*2 B), col = kv*2 bytes
#pragma unroll
  for (int p = 0; p < 2; ++p) {
    int flat = p * 4096 + w * 1024 + lane * 16;
    int row = flat >> 7;
    int colb = (flat & 127) ^ ((row & 7) << 4);
    ksrc[p] = (const char*)qkv + ((size_t)(b * LSEQ + row) * 3072 + 1024 + h * 64) * 2 + colb;
    vsrc[p] = (const char*)vT + ((size_t)(bh * 64 + row) * 1024) * 2 + colb;
  }

  // STAGE(tile, slot): 4 loads/wave (2 K + 2 V)
  auto STAGE = [&](int tt, int s) {
    size_t koff = (size_t)tt * (64 * 3072 * 2);
    size_t voff = (size_t)tt * 128;           // 64 kv * 2 B
#pragma unroll
    for (int p = 0; p < 2; ++p) {
      gload_lds16(ksrc[p] + koff, SM + s * 8192 + p * 4096 + w * 1024);
      gload_lds16(vsrc[p] + voff, SM + 24576 + s * 8192 + p * 4096 + w * 1024);
    }
  };

  f32x4 zero = {0.f, 0.f, 0.f, 0.f};
  f32x4 o[4] = {zero, zero, zero, zero};
  f32x4 o2[4] = {zero, zero, zero, zero};
  float lrow = 0.f, lrow2 = 0.f;

  // prologue: stage tiles 0,1 into slots 0,1; wait tile 0 only
  STAGE(0, 0);
  STAGE(1, 1);
  asm volatile("s_waitcnt vmcnt(4)" ::: "memory");
  asm volatile("s_barrier" ::: "memory");

  int s0 = 0;
  for (int t = 0; t < 16; ++t) {
    int s2 = s0 + 2; if (s2 >= 3) s2 -= 3;
    if (t + 2 < 16) STAGE(t + 2, s2);
    // ---- S^T = K @ Q^T for both q-sets: 16 mfma, K-frag loaded once ----
    f32x4 s4[4] = {zero, zero, zero, zero};
    f32x4 s4b[4] = {zero, zero, zero, zero};
    __builtin_amdgcn_s_setprio(1);
#pragma unroll
    for (int c = 0; c < 4; ++c)
#pragma unroll
      for (int ks = 0; ks < 2; ++ks) {
        int key = c * 16 + l15;
        bf16x8 ak = *(const bf16x8*)(SM + s0 * 8192 + key * 128 +
                                     ((ks * 64 + g * 16) ^ ((key & 7) << 4)));
        s4[c]  = __builtin_amdgcn_mfma_f32_16x16x32_bf16(ak, aq[ks],  s4[c],  0, 0, 0);
        s4b[c] = __builtin_amdgcn_mfma_f32_16x16x32_bf16(ak, aq2[ks], s4b[c], 0, 0, 0);
      }
    __builtin_amdgcn_s_setprio(0);
    // ---- softmax (no max) + pack + exchange, per q-set; l-reduce deferred --
    unsigned pa[2][4], pa2[2][4];
    int gl = (g & 1) * 2;
#pragma unroll
    for (int s = 0; s < 2; ++s) {
      float p16[16], sump = 0.f;
#pragma unroll
      for (int c = 0; c < 4; ++c)
#pragma unroll
        for (int r = 0; r < 4; ++r) {
          float p = exp2f(s ? s4b[c][r] : s4[c][r]);
          p16[c * 4 + r] = p;
          sump += p;
        }
      if (s) lrow2 += sump; else lrow += sump;
      unsigned pk[8];
#pragma unroll
      for (int c = 0; c < 4; ++c)
#pragma unroll
        for (int m = 0; m < 2; ++m)
          asm("v_cvt_pk_bf16_f32 %0, %1, %2"
              : "=v"(pk[c * 2 + m]) : "v"(p16[c * 4 + 2 * m]), "v"(p16[c * 4 + 2 * m + 1]));
#pragma unroll
      for (int kb = 0; kb < 2; ++kb)
#pragma unroll
        for (int wv = 0; wv < 4; ++wv) {
          int srcl = l15 + (gl + (wv >> 1)) * 16;
          unsigned vA = (unsigned)__shfl((int)pk[kb * 4 + (wv & 1)], srcl);
          unsigned vB = (unsigned)__shfl((int)pk[kb * 4 + 2 + (wv & 1)], srcl);
          if (s) pa2[kb][wv] = (g >> 1) ? vB : vA;
          else   pa[kb][wv]  = (g >> 1) ? vB : vA;
        }
    }
    // ---- O += P @ V for both q-sets (V-frag loaded once) ----
    union PU { unsigned u[4]; bf16x8 v; };
    PU pu[2], pu2[2];
#pragma unroll
    for (int kb = 0; kb < 2; ++kb)
#pragma unroll
      for (int i = 0; i < 4; ++i) { pu[kb].u[i] = pa[kb][i]; pu2[kb].u[i] = pa2[kb][i]; }
    __builtin_amdgcn_s_setprio(1);
#pragma unroll
    for (int kb = 0; kb < 2; ++kb)
#pragma unroll
      for (int nb = 0; nb < 4; ++nb) {
        int d = nb * 16 + l15;
        bf16x8 bv = *(const bf16x8*)(SM + 24576 + s0 * 8192 + d * 128 +
                                     ((kb * 64 + g * 16) ^ ((d & 7) << 4)));
        o[nb]  = __builtin_amdgcn_mfma_f32_16x16x32_bf16(pu[kb].v,  bv, o[nb],  0, 0, 0);
        o2[nb] = __builtin_amdgcn_mfma_f32_16x16x32_bf16(pu2[kb].v, bv, o2[nb], 0, 0, 0);
      }
    __builtin_amdgcn_s_setprio(0);
    // ---- end of tile: t+1's loads must land; t+2's stay in flight ----
    if (t + 2 < 16)      asm volatile("s_waitcnt vmcnt(4)" ::: "memory");
    else if (t + 1 < 16) asm volatile("s_waitcnt vmcnt(0)" ::: "memory");
    if (t + 1 < 16)      asm volatile("s_barrier" ::: "memory");
    s0 = s0 + 1; if (s0 >= 3) s0 -= 3;
  }
  // ---- epilogue: deferred l-reduce, then O / l per q-set ----
  lrow  += __shfl_xor(lrow, 16);  lrow  += __shfl_xor(lrow, 32);
  lrow2 += __shfl_xor(lrow2, 16); lrow2 += __shfl_xor(lrow2, 32);
#pragma unroll
  for (int s = 0; s < 2; ++s) {
    float inv = 1.0f / (s ? lrow2 : lrow);
    if (lane < 16) lbuf[w * 16 + lane] = inv;
    f32x4 rl = *(const f32x4*)&lbuf[w * 16 + g * 4];
#pragma unroll
    for (int nb = 0; nb < 4; ++nb)
#pragma unroll
      for (int r = 0; r < 4; ++r) {
        int qrow = qt * 128 + s * 64 + w * 16 + g * 4 + r;
        const f32x4& oo = s ? o2[nb] : o[nb];
        aout[(size_t)(b * LSEQ + qrow) * 1024 + h * 64 + nb * 16 + l15] =
            f2bf(oo[r] * rl[r]);
      }
  }
}

// ---------------- launch ---------------------------------------------------
extern "C" void kernel_launch(void* const* d_in, const int* in_sizes, int n_in,
                              void* d_out, int out_size, void* d_ws, size_t ws_size,
                              hipStream_t stream) {
  const float* x      = (const float*)d_in[0];
  const float* c      = (const float*)d_in[1];
  const float* ln1_w  = (const float*)d_in[2];
  const float* ln1_b  = (const float*)d_in[3];
  const float* ln2_w  = (const float*)d_in[4];
  const float* ln2_b  = (const float*)d_in[5];
  const float* ada_w  = (const float*)d_in[6];
  const float* ada_b  = (const float*)d_in[7];
  const float* qkv_w  = (const float*)d_in[8];
  const float* qkv_b  = (const float*)d_in[9];
  const float* proj_w = (const float*)d_in[10];
  const float* proj_b = (const float*)d_in[11];
  const float* fc1_w  = (const float*)d_in[12];
  const float* fc1_b  = (const float*)d_in[13];
  const float* fc2_w  = (const float*)d_in[14];
  const float* fc2_b  = (const float*)d_in[15];
  float* out = (float*)d_out;
  char* ws = (char*)d_ws;

  // workspace layout (bytes); high-water = 109,248,512 (~104.2 MB)
  ushort_t* qkvT  = (ushort_t*)(ws + 0);          // [3072][1024] bf16   6.0 MB
  ushort_t* projT = (ushort_t*)(ws + 6291456);    // [1024][1024]        2.0 MB
  ushort_t* fc1T  = (ushort_t*)(ws + 8388608);    // [4096][1024]        8.0 MB
  ushort_t* fc2T  = (ushort_t*)(ws + 16777216);   // [1024][4096]        8.0 MB
  float*    ssg   = (float*)(ws + 25165824);      // [8][6144] f32       0.2 MB
  ushort_t* hbuf  = (ushort_t*)(ws + 25362432);   // [8192][1024] bf16  16.0 MB
  ushort_t* abuf  = hbuf;                         // alias (ln1 out dead by then)
  ushort_t* qkvb  = (ushort_t*)(ws + 42139648);   // [8192][4096] max   64.0 MB
  // vT occupies the top 16 MB of the qkvb slab (qkv uses only 48 MB of it;
  // the 64 MB gelu reuse happens after attn, when vT is dead).
  ushort_t* vTb   = (ushort_t*)(ws + 92471296);   // [128][64][1024]    16.0 MB
  if (ws_size < (size_t)109248512) return;        // guard: avoid OOB -> GPU fault

  tcast_kernel<<<dim3(96, 32),  256, 0, stream>>>(qkv_w,  qkvT, 1024, 3072);
  tcast_kernel<<<dim3(32, 32),  256, 0, stream>>>(proj_w, projT, 1024, 1024);
  tcast_kernel<<<dim3(128, 32), 256, 0, stream>>>(fc1_w,  fc1T, 1024, 4096);
  tcast_kernel<<<dim3(32, 128), 256, 0, stream>>>(fc2_w,  fc2T, 4096, 1024);
  ada_kernel<<<dim3(24, 8), 256, 0, stream>>>(c, ada_w, ada_b, ssg);

  ln_mod_kernel<<<8192, 256, 0, stream>>>(x, ln1_w, ln1_b, ssg, 0, 1024, hbuf);
  gemm_kernel<0><<<1536, 256, 0, stream>>>(hbuf, qkvT, qkv_b, nullptr,
                                           nullptr, nullptr, qkvb, 3072, 1024, 0, 2);
  vtrans_kernel<<<dim3(128, 8), 256, 0, stream>>>(qkvb, vTb);
  attn_kernel<<<dim3(8, 128), 256, 0, stream>>>(qkvb, vTb, abuf);
  gemm_kernel<1><<<512, 256, 0, stream>>>(abuf, projT, proj_b, ssg,
                                          x, out, nullptr, 1024, 1024, 2048, 2);
  ln_mod_kernel<<<8192, 256, 0, stream>>>(out, ln2_w, ln2_b, ssg, 3072, 4096, hbuf);
  gemm_kernel<2><<<2048, 256, 0, stream>>>(hbuf, fc1T, fc1_b, nullptr,
                                           nullptr, nullptr, qkvb, 4096, 1024, 0, 2);
  gemm_kernel<3><<<512, 256, 0, stream>>>(qkvb, fc2T, fc2_b, ssg,
                                          out, out, nullptr, 1024, 4096, 5120, 1);
}

// Round 18
// 415.152 us; speedup vs baseline: 1.0947x; 1.0947x over previous
//
#include <hip/hip_runtime.h>
#include <math.h>

#define DMODEL 1024
#define SIXD   6144
#define NHEAD  16
#define HEADD  64
#define LSEQ   1024
#define NBATCH 8
#define MROWS  8192   // NBATCH*LSEQ

typedef unsigned short ushort_t;
typedef __attribute__((ext_vector_type(8))) short bf16x8;
typedef __attribute__((ext_vector_type(4))) float f32x4;

__device__ __forceinline__ unsigned short f2bf(float f) {
  unsigned int u = __float_as_uint(f);
  u += 0x7fff + ((u >> 16) & 1);          // round-to-nearest-even
  return (unsigned short)(u >> 16);
}

__device__ __forceinline__ void gload_lds16(const void* g, void* l) {
  __builtin_amdgcn_global_load_lds(
      (const __attribute__((address_space(1))) unsigned int*)g,
      (__attribute__((address_space(3))) unsigned int*)l, 16, 0, 0);
}

// ---------------- weight transpose + cast: W[K][N] f32 -> WT[N][K] bf16 ----
__global__ void tcast_kernel(const float* __restrict__ W, ushort_t* __restrict__ WT,
                             int K, int N) {
  __shared__ float tile[32][33];
  int tx = threadIdx.x & 31, ty = threadIdx.x >> 5;
  int n0 = blockIdx.x * 32, k0 = blockIdx.y * 32;
#pragma unroll
  for (int r = 0; r < 4; ++r)
    tile[ty + 8*r][tx] = W[(size_t)(k0 + ty + 8*r) * N + n0 + tx];
  __syncthreads();
#pragma unroll
  for (int r = 0; r < 4; ++r)
    WT[(size_t)(n0 + ty + 8*r) * K + k0 + tx] = f2bf(tile[tx][ty + 8*r]);
}

// ---------------- V transpose: qkv[row][2048+h*64+d] -> vT[bh][d][kv] ------
__global__ __launch_bounds__(256) void vtrans_kernel(
    const ushort_t* __restrict__ qkvb, ushort_t* __restrict__ vT) {
  __shared__ ushort_t tile[128][66];   // pad 66: conflict-light transpose
  int bh = blockIdx.x;                 // 0..127
  int kt = blockIdx.y;                 // 0..7 (128 kv rows each)
  int b = bh >> 4, h = bh & 15;
  int tid = threadIdx.x;
#pragma unroll
  for (int i = 0; i < 4; ++i) {
    int flat = tid + 256 * i;          // 1024 chunks of 8 elems
    int r = flat >> 3, c8 = flat & 7;
    bf16x8 v = *(const bf16x8*)((const short*)qkvb +
        (size_t)(b * LSEQ + kt * 128 + r) * 3072 + 2048 + h * 64 + c8 * 8);
#pragma unroll
    for (int j = 0; j < 8; ++j) tile[r][c8 * 8 + j] = (ushort_t)v[j];
  }
  __syncthreads();
#pragma unroll
  for (int i = 0; i < 4; ++i) {
    int d = i * 16 + (tid >> 4);
    int kc = tid & 15;
    bf16x8 ov;
#pragma unroll
    for (int j = 0; j < 8; ++j) ov[j] = (short)tile[kc * 8 + j][d];
    *(bf16x8*)((short*)vT + (size_t)(bh * 64 + d) * 1024 + kt * 128 + kc * 8) = ov;
  }
}

// ---------------- adaLN: ssg[b][j] = silu(c[b]) @ ada_w[:,j] + ada_b[j] ----
__global__ void ada_kernel(const float* __restrict__ c, const float* __restrict__ ada_w,
                           const float* __restrict__ ada_b, float* __restrict__ ssg) {
  __shared__ float s[DMODEL];
  int b = blockIdx.y;
  int j = blockIdx.x * 256 + threadIdx.x;
  for (int i = threadIdx.x; i < DMODEL; i += 256) {
    float v = c[b * DMODEL + i];
    s[i] = v / (1.0f + __expf(-v));
  }
  __syncthreads();
  float acc = ada_b[j];
#pragma unroll 8
  for (int k = 0; k < DMODEL; ++k)
    acc = fmaf(s[k], ada_w[(size_t)k * SIXD + j], acc);
  ssg[b * SIXD + j] = acc;
}

// ---------------- LayerNorm + modulate + cast to bf16 ---------------------
__global__ __launch_bounds__(256) void ln_mod_kernel(
    const float* __restrict__ xin, const float* __restrict__ lw,
    const float* __restrict__ lb, const float* __restrict__ ssg,
    int shift_off, int scale_off, ushort_t* __restrict__ outB) {
  int row = blockIdx.x;
  int b = row >> 10;
  int tid = threadIdx.x;
  float4 v = ((const float4*)xin)[(size_t)row * 256 + tid];
  float sum = v.x + v.y + v.z + v.w;
  float sq  = v.x*v.x + v.y*v.y + v.z*v.z + v.w*v.w;
#pragma unroll
  for (int m = 32; m; m >>= 1) { sum += __shfl_xor(sum, m); sq += __shfl_xor(sq, m); }
  __shared__ float rbuf[8];
  int w = tid >> 6, lane = tid & 63;
  if (lane == 0) { rbuf[w] = sum; rbuf[4 + w] = sq; }
  __syncthreads();
  sum = rbuf[0] + rbuf[1] + rbuf[2] + rbuf[3];
  sq  = rbuf[4] + rbuf[5] + rbuf[6] + rbuf[7];
  float mu  = sum * (1.0f / 1024.0f);
  float var = sq * (1.0f / 1024.0f) - mu * mu;
  float rs  = rsqrtf(var + 1e-5f);
  const float* sg = ssg + b * SIXD;
  float vv[4] = {v.x, v.y, v.z, v.w};
  ushort4 pk;
  unsigned short* pks = (unsigned short*)&pk;
#pragma unroll
  for (int j = 0; j < 4; ++j) {
    int d = tid * 4 + j;
    float h = (vv[j] - mu) * rs * lw[d] + lb[d];
    h = h * (1.0f + sg[scale_off + d]) + sg[shift_off + d];
    pks[j] = f2bf(h);
  }
  ((ushort4*)outB)[(size_t)row * 256 + tid] = pk;
}

// ---------------- GEMM: C[M][N] = A[M][K]bf16 @ BT[N][K]bf16^T + epilogue --
// 128x128 tile, BK=64, 256 thr; 2-phase double-buffer; 3-level block remap
// (XCD chunk -> GX-column groups over 8 by-rows, L2-sized working sets).
// BK=64 is the verified optimum: BK=32 ring-3 (r17) hit a 4-way LDS bank
// conflict (64B rows can't spread 16 row-parities over 8 XOR slots) and
// doubled barrier count -> -9%.
template <int EPI>
__global__ __launch_bounds__(256, 2) void gemm_kernel(
    const ushort_t* __restrict__ A, const ushort_t* __restrict__ BT,
    const float* __restrict__ bias, const float* __restrict__ ssg,
    const float* resid, float* outF, ushort_t* __restrict__ outB,
    int N, int K, int gate_off, int gxs) {
  __shared__ __align__(16) char SM[65536];   // buf0 [0,32K): A|B ; buf1 [32K,64K)
  int tid = threadIdx.x, lane = tid & 63, w = tid >> 6;
  int l15 = lane & 15, g = lane >> 4;
  // 3-level remap (nby = 64 -> nby_x = 8 rows per XCD, both powers of 2)
  int orig = blockIdx.x;
  int xcd = orig & 7;
  int idx = orig >> 3;
  int bxi = idx & ((1 << gxs) - 1);
  int byl = (idx >> gxs) & 7;
  int bxg = idx >> (gxs + 3);
  int bx = (bxg << gxs) + bxi;
  int by = (xcd << 3) + byl;
  int m0 = by * 128, n0 = bx * 128;
  int wrow = (w >> 1) * 64, wcol = (w & 1) * 64;
  f32x4 zero = {0.f, 0.f, 0.f, 0.f};
  f32x4 acc[4][4];
#pragma unroll
  for (int i = 0; i < 4; ++i)
#pragma unroll
    for (int j = 0; j < 4; ++j) acc[i][j] = zero;

  // staging sources (pre-swizzled, tile-invariant)
  const char* asrc[4];
  const char* bsrc[4];
#pragma unroll
  for (int ch = 0; ch < 4; ++ch) {
    int flat = ch * 4096 + tid * 16;
    int row = flat >> 7;
    int colb = (flat & 127) ^ ((row & 7) << 4);   // inverse-swizzled source
    asrc[ch] = (const char*)A  + ((size_t)(m0 + row) * K) * 2 + colb;
    bsrc[ch] = (const char*)BT + ((size_t)(n0 + row) * K) * 2 + colb;
  }

  int T = K >> 6;
  // prologue: stage tile 0 into buf 0 (8 loads in flight)
#pragma unroll
  for (int ch = 0; ch < 4; ++ch)
    gload_lds16(asrc[ch], SM + ch * 4096 + tid * 16);
#pragma unroll
  for (int ch = 0; ch < 4; ++ch)
    gload_lds16(bsrc[ch], SM + 16384 + ch * 4096 + tid * 16);

  for (int t = 0; t < T; ++t) {
    if (t + 1 < T) {   // issue next tile's 8 loads, then wait only tile-t's
      char* base = SM + ((t + 1) & 1) * 32768;
      size_t ko = (size_t)(t + 1) * 128;
#pragma unroll
      for (int ch = 0; ch < 4; ++ch)
        gload_lds16(asrc[ch] + ko, base + ch * 4096 + tid * 16);
#pragma unroll
      for (int ch = 0; ch < 4; ++ch)
        gload_lds16(bsrc[ch] + ko, base + 16384 + ch * 4096 + tid * 16);
      asm volatile("s_waitcnt vmcnt(8)" ::: "memory");
    } else {
      asm volatile("s_waitcnt vmcnt(0)" ::: "memory");
    }
    asm volatile("s_barrier" ::: "memory");   // all waves: tile-t data landed
    const char* ab = SM + (t & 1) * 32768;
    const char* bb = ab + 16384;
#pragma unroll
    for (int kk = 0; kk < 2; ++kk) {
      bf16x8 af[4], bfr[4];
#pragma unroll
      for (int i = 0; i < 4; ++i) {
        int ar = wrow + i * 16 + l15;
        af[i]  = *(const bf16x8*)(ab + ar * 128 + ((kk * 64 + g * 16) ^ ((ar & 7) << 4)));
        int br = wcol + i * 16 + l15;
        bfr[i] = *(const bf16x8*)(bb + br * 128 + ((kk * 64 + g * 16) ^ ((br & 7) << 4)));
      }
#pragma unroll
      for (int i = 0; i < 4; ++i)
#pragma unroll
        for (int j = 0; j < 4; ++j)
          acc[i][j] = __builtin_amdgcn_mfma_f32_16x16x32_bf16(af[i], bfr[j], acc[i][j], 0, 0, 0);
    }
    // all ds_reads of buf[t&1] retired before each wave's MFMAs issued
    // (lgkmcnt dep), so after this barrier the buffer may be overwritten.
    asm volatile("s_barrier" ::: "memory");
  }
  // epilogue
#pragma unroll
  for (int i = 0; i < 4; ++i)
#pragma unroll
    for (int j = 0; j < 4; ++j)
#pragma unroll
      for (int r = 0; r < 4; ++r) {
        int grow = m0 + wrow + i * 16 + g * 4 + r;
        int gcol = n0 + wcol + j * 16 + l15;
        float v = acc[i][j][r] + bias[gcol];
        if (EPI == 0) {
          outB[(size_t)grow * N + gcol] = f2bf(v);
        } else if (EPI == 1 || EPI == 3) {
          int bb2 = grow >> 10;
          float gate = ssg[bb2 * SIXD + gate_off + gcol];
          size_t idx2 = (size_t)grow * N + gcol;   // N==1024 here
          outF[idx2] = resid[idx2] + gate * v;
        } else {  // gelu tanh-approx
          float u = v;
          float t2 = 0.7978845608028654f * (u + 0.044715f * u * u * u);
          float e = __expf(2.0f * t2);
          float th = 1.0f - 2.0f / (e + 1.0f);
          outB[(size_t)grow * N + gcol] = f2bf(0.5f * u * (1.0f + th));
        }
      }
}

// ---------------- flash attention (ring-3 K/V, counted vmcnt, 2 q-tiles) ---
// grid (8 q-tiles of 128 rows, 128 b*h), 256 threads (4 waves).
// T3+T4: 3 K/V slots; iter t stages t+2, end-of-tile waits vmcnt(4) (t+1's
// loads land, t+2's stay in flight across the raw s_barrier). Hazard ledger
// HW-verified in r16. No-max softmax; l-reduce deferred to epilogue.
__global__ __launch_bounds__(256, 2) void attn_kernel(
    const ushort_t* __restrict__ qkv,   // [8192][3072] bf16 (q|k|v)
    const ushort_t* __restrict__ vT,    // [128 bh][64 d][1024 kv] bf16
    ushort_t* __restrict__ aout) {      // [8192][1024] bf16
  // K slots [0,24576) ; V^T slots [24576,49152) ; lbuf [49152,+256)
  __shared__ __align__(16) char SM[49408];
  float* lbuf = (float*)(SM + 49152);
  int tid = threadIdx.x, lane = tid & 63, w = tid >> 6;
  int l15 = lane & 15, g = lane >> 4;
  int qt = blockIdx.x, bh = blockIdx.y;
  int b = bh >> 4, h = bh & 15;
  const float sc = 0.18033688f;  // (1/sqrt(64)) * log2(e)

  // Q fragments for both q-sets (B operand), scaled by sc (bf16 repack)
  bf16x8 aq[2], aq2[2];
  {
    int qrow = qt * 128 + w * 16 + l15;
    const short* qp = (const short*)qkv + (size_t)(b * LSEQ + qrow) * 3072 + h * 64 + g * 8;
    aq[0] = *(const bf16x8*)qp;
    aq[1] = *(const bf16x8*)(qp + 32);
    const short* qp2 = qp + (size_t)64 * 3072;
    aq2[0] = *(const bf16x8*)qp2;
    aq2[1] = *(const bf16x8*)(qp2 + 32);
#pragma unroll
    for (int ks = 0; ks < 2; ++ks) {
#pragma unroll
      for (int s = 0; s < 2; ++s) {
        union { bf16x8 v; unsigned short u[8]; } qi, qo;
        qi.v = s ? aq2[ks] : aq[ks];
#pragma unroll
        for (int j = 0; j < 8; j += 2) {
          float lo = __uint_as_float((unsigned)qi.u[j] << 16) * sc;
          float hi = __uint_as_float((unsigned)qi.u[j + 1] << 16) * sc;
          unsigned pkd;
          asm("v_cvt_pk_bf16_f32 %0, %1, %2" : "=v"(pkd) : "v"(lo), "v"(hi));
          qo.u[j] = (unsigned short)(pkd & 0xffff);
          qo.u[j + 1] = (unsigned short)(pkd >> 16);
        }
        if (s) aq2[ks] = qo.v; else aq[ks] = qo.v;
      }
    }
  }

  // staging sources (pre-swizzled; tile-invariant part)
  const char* ksrc[2];   // K rows = kv (stride 3072*2 B)
  const char* vsrc[2];   // V^T rows = d (stride 1024*2 B), col = kv*2 bytes
#pragma unroll
  for (int p = 0; p < 2; ++p) {
    int flat = p * 4096 + w * 1024 + lane * 16;
    int row = flat >> 7;
    int colb = (flat & 127) ^ ((row & 7) << 4);
    ksrc[p] = (const char*)qkv + ((size_t)(b * LSEQ + row) * 3072 + 1024 + h * 64) * 2 + colb;
    vsrc[p] = (const char*)vT + ((size_t)(bh * 64 + row) * 1024) * 2 + colb;
  }

  // STAGE(tile, slot): 4 loads/wave (2 K + 2 V)
  auto STAGE = [&](int tt, int s) {
    size_t koff = (size_t)tt * (64 * 3072 * 2);
    size_t voff = (size_t)tt * 128;           // 64 kv * 2 B
#pragma unroll
    for (int p = 0; p < 2; ++p) {
      gload_lds16(ksrc[p] + koff, SM + s * 8192 + p * 4096 + w * 1024);
      gload_lds16(vsrc[p] + voff, SM + 24576 + s * 8192 + p * 4096 + w * 1024);
    }
  };

  f32x4 zero = {0.f, 0.f, 0.f, 0.f};
  f32x4 o[4] = {zero, zero, zero, zero};
  f32x4 o2[4] = {zero, zero, zero, zero};
  float lrow = 0.f, lrow2 = 0.f;

  // prologue: stage tiles 0,1 into slots 0,1; wait tile 0 only
  STAGE(0, 0);
  STAGE(1, 1);
  asm volatile("s_waitcnt vmcnt(4)" ::: "memory");
  asm volatile("s_barrier" ::: "memory");

  int s0 = 0;
  for (int t = 0; t < 16; ++t) {
    int s2 = s0 + 2; if (s2 >= 3) s2 -= 3;
    if (t + 2 < 16) STAGE(t + 2, s2);
    // ---- S^T = K @ Q^T for both q-sets: 16 mfma, K-frag loaded once ----
    f32x4 s4[4] = {zero, zero, zero, zero};
    f32x4 s4b[4] = {zero, zero, zero, zero};
    __builtin_amdgcn_s_setprio(1);
#pragma unroll
    for (int c = 0; c < 4; ++c)
#pragma unroll
      for (int ks = 0; ks < 2; ++ks) {
        int key = c * 16 + l15;
        bf16x8 ak = *(const bf16x8*)(SM + s0 * 8192 + key * 128 +
                                     ((ks * 64 + g * 16) ^ ((key & 7) << 4)));
        s4[c]  = __builtin_amdgcn_mfma_f32_16x16x32_bf16(ak, aq[ks],  s4[c],  0, 0, 0);
        s4b[c] = __builtin_amdgcn_mfma_f32_16x16x32_bf16(ak, aq2[ks], s4b[c], 0, 0, 0);
      }
    __builtin_amdgcn_s_setprio(0);
    // ---- softmax (no max) + pack + exchange, per q-set; l-reduce deferred --
    unsigned pa[2][4], pa2[2][4];
    int gl = (g & 1) * 2;
#pragma unroll
    for (int s = 0; s < 2; ++s) {
      float p16[16], sump = 0.f;
#pragma unroll
      for (int c = 0; c < 4; ++c)
#pragma unroll
        for (int r = 0; r < 4; ++r) {
          float p = exp2f(s ? s4b[c][r] : s4[c][r]);
          p16[c * 4 + r] = p;
          sump += p;
        }
      if (s) lrow2 += sump; else lrow += sump;
      unsigned pk[8];
#pragma unroll
      for (int c = 0; c < 4; ++c)
#pragma unroll
        for (int m = 0; m < 2; ++m)
          asm("v_cvt_pk_bf16_f32 %0, %1, %2"
              : "=v"(pk[c * 2 + m]) : "v"(p16[c * 4 + 2 * m]), "v"(p16[c * 4 + 2 * m + 1]));
#pragma unroll
      for (int kb = 0; kb < 2; ++kb)
#pragma unroll
        for (int wv = 0; wv < 4; ++wv) {
          int srcl = l15 + (gl + (wv >> 1)) * 16;
          unsigned vA = (unsigned)__shfl((int)pk[kb * 4 + (wv & 1)], srcl);
          unsigned vB = (unsigned)__shfl((int)pk[kb * 4 + 2 + (wv & 1)], srcl);
          if (s) pa2[kb][wv] = (g >> 1) ? vB : vA;
          else   pa[kb][wv]  = (g >> 1) ? vB : vA;
        }
    }
    // ---- O += P @ V for both q-sets (V-frag loaded once) ----
    union PU { unsigned u[4]; bf16x8 v; };
    PU pu[2], pu2[2];
#pragma unroll
    for (int kb = 0; kb < 2; ++kb)
#pragma unroll
      for (int i = 0; i < 4; ++i) { pu[kb].u[i] = pa[kb][i]; pu2[kb].u[i] = pa2[kb][i]; }
    __builtin_amdgcn_s_setprio(1);
#pragma unroll
    for (int kb = 0; kb < 2; ++kb)
#pragma unroll
      for (int nb = 0; nb < 4; ++nb) {
        int d = nb * 16 + l15;
        bf16x8 bv = *(const bf16x8*)(SM + 24576 + s0 * 8192 + d * 128 +
                                     ((kb * 64 + g * 16) ^ ((d & 7) << 4)));
        o[nb]  = __builtin_amdgcn_mfma_f32_16x16x32_bf16(pu[kb].v,  bv, o[nb],  0, 0, 0);
        o2[nb] = __builtin_amdgcn_mfma_f32_16x16x32_bf16(pu2[kb].v, bv, o2[nb], 0, 0, 0);
      }
    __builtin_amdgcn_s_setprio(0);
    // ---- end of tile: t+1's loads must land; t+2's stay in flight ----
    if (t + 2 < 16)      asm volatile("s_waitcnt vmcnt(4)" ::: "memory");
    else if (t + 1 < 16) asm volatile("s_waitcnt vmcnt(0)" ::: "memory");
    if (t + 1 < 16)      asm volatile("s_barrier" ::: "memory");
    s0 = s0 + 1; if (s0 >= 3) s0 -= 3;
  }
  // ---- epilogue: deferred l-reduce, then O / l per q-set ----
  lrow  += __shfl_xor(lrow, 16);  lrow  += __shfl_xor(lrow, 32);
  lrow2 += __shfl_xor(lrow2, 16); lrow2 += __shfl_xor(lrow2, 32);
#pragma unroll
  for (int s = 0; s < 2; ++s) {
    float inv = 1.0f / (s ? lrow2 : lrow);
    if (lane < 16) lbuf[w * 16 + lane] = inv;
    f32x4 rl = *(const f32x4*)&lbuf[w * 16 + g * 4];
#pragma unroll
    for (int nb = 0; nb < 4; ++nb)
#pragma unroll
      for (int r = 0; r < 4; ++r) {
        int qrow = qt * 128 + s * 64 + w * 16 + g * 4 + r;
        const f32x4& oo = s ? o2[nb] : o[nb];
        aout[(size_t)(b * LSEQ + qrow) * 1024 + h * 64 + nb * 16 + l15] =
            f2bf(oo[r] * rl[r]);
      }
  }
}

// ---------------- launch ---------------------------------------------------
extern "C" void kernel_launch(void* const* d_in, const int* in_sizes, int n_in,
                              void* d_out, int out_size, void* d_ws, size_t ws_size,
                              hipStream_t stream) {
  const float* x      = (const float*)d_in[0];
  const float* c      = (const float*)d_in[1];
  const float* ln1_w  = (const float*)d_in[2];
  const float* ln1_b  = (const float*)d_in[3];
  const float* ln2_w  = (const float*)d_in[4];
  const float* ln2_b  = (const float*)d_in[5];
  const float* ada_w  = (const float*)d_in[6];
  const float* ada_b  = (const float*)d_in[7];
  const float* qkv_w  = (const float*)d_in[8];
  const float* qkv_b  = (const float*)d_in[9];
  const float* proj_w = (const float*)d_in[10];
  const float* proj_b = (const float*)d_in[11];
  const float* fc1_w  = (const float*)d_in[12];
  const float* fc1_b  = (const float*)d_in[13];
  const float* fc2_w  = (const float*)d_in[14];
  const float* fc2_b  = (const float*)d_in[15];
  float* out = (float*)d_out;
  char* ws = (char*)d_ws;

  // workspace layout (bytes); high-water = 109,248,512 (~104.2 MB)
  ushort_t* qkvT  = (ushort_t*)(ws + 0);          // [3072][1024] bf16   6.0 MB
  ushort_t* projT = (ushort_t*)(ws + 6291456);    // [1024][1024]        2.0 MB
  ushort_t* fc1T  = (ushort_t*)(ws + 8388608);    // [4096][1024]        8.0 MB
  ushort_t* fc2T  = (ushort_t*)(ws + 16777216);   // [1024][4096]        8.0 MB
  float*    ssg   = (float*)(ws + 25165824);      // [8][6144] f32       0.2 MB
  ushort_t* hbuf  = (ushort_t*)(ws + 25362432);   // [8192][1024] bf16  16.0 MB
  ushort_t* abuf  = hbuf;                         // alias (ln1 out dead by then)
  ushort_t* qkvb  = (ushort_t*)(ws + 42139648);   // [8192][4096] max   64.0 MB
  // vT occupies the top 16 MB of the qkvb slab (qkv uses only 48 MB of it;
  // the 64 MB gelu reuse happens after attn, when vT is dead).
  ushort_t* vTb   = (ushort_t*)(ws + 92471296);   // [128][64][1024]    16.0 MB
  if (ws_size < (size_t)109248512) return;        // guard: avoid OOB -> GPU fault

  tcast_kernel<<<dim3(96, 32),  256, 0, stream>>>(qkv_w,  qkvT, 1024, 3072);
  tcast_kernel<<<dim3(32, 32),  256, 0, stream>>>(proj_w, projT, 1024, 1024);
  tcast_kernel<<<dim3(128, 32), 256, 0, stream>>>(fc1_w,  fc1T, 1024, 4096);
  tcast_kernel<<<dim3(32, 128), 256, 0, stream>>>(fc2_w,  fc2T, 4096, 1024);
  ada_kernel<<<dim3(24, 8), 256, 0, stream>>>(c, ada_w, ada_b, ssg);

  ln_mod_kernel<<<8192, 256, 0, stream>>>(x, ln1_w, ln1_b, ssg, 0, 1024, hbuf);
  gemm_kernel<0><<<1536, 256, 0, stream>>>(hbuf, qkvT, qkv_b, nullptr,
                                           nullptr, nullptr, qkvb, 3072, 1024, 0, 2);
  vtrans_kernel<<<dim3(128, 8), 256, 0, stream>>>(qkvb, vTb);
  attn_kernel<<<dim3(8, 128), 256, 0, stream>>>(qkvb, vTb, abuf);
  gemm_kernel<1><<<512, 256, 0, stream>>>(abuf, projT, proj_b, ssg,
                                          x, out, nullptr, 1024, 1024, 2048, 2);
  ln_mod_kernel<<<8192, 256, 0, stream>>>(out, ln2_w, ln2_b, ssg, 3072, 4096, hbuf);
  gemm_kernel<2><<<2048, 256, 0, stream>>>(hbuf, fc1T, fc1_b, nullptr,
                                           nullptr, nullptr, qkvb, 4096, 1024, 0, 2);
  gemm_kernel<3><<<512, 256, 0, stream>>>(qkvb, fc2T, fc2_b, ssg,
                                          out, out, nullptr, 1024, 4096, 5120, 1);
}